// Round 9
// baseline (1385.764 us; speedup 1.0000x reference)
//
#include <hip/hip_runtime.h>
#include <hip/hip_cooperative_groups.h>
#include <hip/hip_bf16.h>
#include <math.h>

namespace cg = cooperative_groups;
typedef __hip_bfloat16 bf16;

// ---------------------------------------------------------------------------
// GCNWithEdge: single cooperative mega-kernel, 7 phases w/ grid.sync.
//   P0 cursors+tables  P1 bucket scatter (padded CAP, no scans)
//   P2 per-bucket CSR (deg/dinv/rp/col in-place, LDS)  P3 xWs=dinv*(x@W1)
//   P4 conv1 gather+relu+64->2 proj (8-deep seq adds)  P5 conv2 scalar gather
//   P6 per-edge epilogue -> fp32 out
// R8 lessons: 16-wide load batch regressed gather1 (62->72us, all-loads-drain
// at 32 VGPR) -> 8-deep sequential adds. ~220us of R8 was 10 small dispatches
// + gaps -> fused. Buckets padded to CAP=4608 (mean 4096 + 8 sigma).
// ---------------------------------------------------------------------------

#define CAP 4608

struct MArgs {
    const float* x; const int* src; const int* dst; const int* ea;
    const float* W1; const float* b1;  const float* W2;
    const float* emb0; const float* emb1;
    const float* fcW1; const float* fcb1; const float* fcW2; const float* fcb2;
    float* dinv; int* rp; int* deg; int* cursors;
    float* U; float* E0t; float* E1t; float* Cc;
    float* Qs; float* P; bf16* xWs;
    int* colp;      // padded bucket region in d_out (NB*CAP ints <= out floats)
    float* out;
    int N, E, NB;
};

union __align__(16) Smem {
    struct { unsigned short xs[64][72]; float Ws[64][64]; } g;  // 9216+16384=25600
    struct { int pairs[CAP]; int cnt[256]; int sc[256]; } c;    // 20480
    struct { float w[4096]; } s;                                 // 16384
};

__device__ __forceinline__ unsigned short f2bf_rne(float v) {
    unsigned u = __float_as_uint(v);
    return (unsigned short)((u + 0x7FFFu + ((u >> 16) & 1u)) >> 16);
}

__global__ __launch_bounds__(256, 6) void mega(MArgs a) {
    cg::grid_group grid = cg::this_grid();
    __shared__ Smem sm;
    const int t = threadIdx.x;
    const int b = blockIdx.x;
    const int GT = gridDim.x * 256;

    // ---- P0: cursor init + folded tables (block 0) ----
    for (int i = b * 256 + t; i < a.NB; i += GT) a.cursors[i] = i * CAP;
    if (b == 0) {
        for (int i = t; i < 4096; i += 256) sm.s.w[i] = a.W2[i];
        __syncthreads();
        if (t < 128) {
            int i = t >> 1, c = t & 1;
            float s = 0.f;
            for (int j = 0; j < 64; ++j) s += sm.s.w[i * 64 + j] * a.fcW1[j * 2 + c];
            a.U[i * 2 + c] = s;                  // U = W2 @ fcW1[0:64,:]
        }
        if (t < 40) {
            int i = t >> 1, c = t & 1;
            float s0 = 0.f, s1 = 0.f;
            for (int k = 0; k < 32; ++k) {
                s0 += a.emb0[i * 32 + k] * a.fcW1[(66 + k) * 2 + c];
                s1 += a.emb1[i * 32 + k] * a.fcW1[(98 + k) * 2 + c];
            }
            a.E0t[i * 2 + c] = s0;
            a.E1t[i * 2 + c] = s1;
        }
        if (t == 0) {                            // b2 cancels in h2[s]-h2[d]
            a.Cc[0] = a.fcb1[0];  a.Cc[1] = a.fcb1[1];
            a.Cc[2] = a.fcW1[128]; a.Cc[3] = a.fcW1[129];
            a.Cc[4] = a.fcW1[130]; a.Cc[5] = a.fcW1[131];
            a.Cc[6] = a.fcW2[0];  a.Cc[7] = a.fcW2[1];
            a.Cc[8] = a.fcW2[2];  a.Cc[9] = a.fcW2[3];
            a.Cc[10] = a.fcb2[0]; a.Cc[11] = a.fcb2[1];
        }
    }
    grid.sync();

    // ---- P1: padded-bucket scatter (device atomics on 391 cursors) ----
    for (int e = b * 256 + t; e < a.E; e += GT) {
        int d = a.dst[e];
        int bb = d >> 8;
        int pos = atomicAdd(&a.cursors[bb], 1);
        if (pos < bb * CAP + CAP) a.colp[pos] = ((d & 255) << 17) | a.src[e];
    }
    grid.sync();

    // ---- P2: per-bucket CSR finalize (deg/dinv/rp, col in place) ----
    for (int bb = b; bb < a.NB; bb += gridDim.x) {
        int base = bb * CAP;
        int end = min(a.cursors[bb], base + CAP);
        int ne = end - base;
        for (int i = t; i < ne; i += 256) sm.c.pairs[i] = a.colp[base + i];
        sm.c.cnt[t] = 0;
        __syncthreads();
        for (int i = t; i < ne; i += 256) atomicAdd(&sm.c.cnt[sm.c.pairs[i] >> 17], 1);
        __syncthreads();
        int v = sm.c.cnt[t];
        int n = (bb << 8) + t;
        if (n < a.N) { a.deg[n] = v; a.dinv[n] = rsqrtf((float)v + 1.0f); }
        sm.c.sc[t] = v;
        int xx = v;
        for (int off = 1; off < 256; off <<= 1) {
            __syncthreads();
            int ad = (t >= off) ? sm.c.sc[t - off] : 0;
            __syncthreads();
            xx += ad;
            sm.c.sc[t] = xx;
        }
        __syncthreads();
        int excl = xx - v;
        if (n < a.N) a.rp[n] = base + excl;
        sm.c.cnt[t] = base + excl;               // write cursor
        __syncthreads();
        for (int i = t; i < ne; i += 256) {
            int pv = sm.c.pairs[i];
            int pos = atomicAdd(&sm.c.cnt[pv >> 17], 1);
            a.colp[pos] = pv & 0x1FFFF;
        }
        __syncthreads();
    }
    grid.sync();

    // ---- P3: xWs = dinv * (x @ W1), LDS tile (x as bf16 in LDS) ----
    int tiles = (a.N + 63) >> 6;
    for (int tile = b; tile < tiles; tile += gridDim.x) {
        int n0 = tile << 6;
        for (int i = t; i < 4096; i += 256) sm.g.Ws[i >> 6][i & 63] = a.W1[i];
        for (int i = t; i < 4096; i += 256) {
            int node = i >> 6, k = i & 63;
            float v = (n0 + node < a.N) ? a.x[(size_t)(n0 + node) * 64 + k] : 0.f;
            sm.g.xs[k][node] = f2bf_rne(v);
        }
        __syncthreads();
        int tr = t >> 4, tc = t & 15;
        float acc[4][4] = {};
#pragma unroll 8
        for (int k = 0; k < 64; ++k) {
            ushort4 xq = *(const ushort4*)&sm.g.xs[k][tr * 4];
            float4 wv = *(const float4*)&sm.g.Ws[k][tc * 4];
            float x0 = __uint_as_float((unsigned)xq.x << 16);
            float x1 = __uint_as_float((unsigned)xq.y << 16);
            float x2 = __uint_as_float((unsigned)xq.z << 16);
            float x3 = __uint_as_float((unsigned)xq.w << 16);
            acc[0][0] = fmaf(x0, wv.x, acc[0][0]);
            acc[0][1] = fmaf(x0, wv.y, acc[0][1]);
            acc[0][2] = fmaf(x0, wv.z, acc[0][2]);
            acc[0][3] = fmaf(x0, wv.w, acc[0][3]);
            acc[1][0] = fmaf(x1, wv.x, acc[1][0]);
            acc[1][1] = fmaf(x1, wv.y, acc[1][1]);
            acc[1][2] = fmaf(x1, wv.z, acc[1][2]);
            acc[1][3] = fmaf(x1, wv.w, acc[1][3]);
            acc[2][0] = fmaf(x2, wv.x, acc[2][0]);
            acc[2][1] = fmaf(x2, wv.y, acc[2][1]);
            acc[2][2] = fmaf(x2, wv.z, acc[2][2]);
            acc[2][3] = fmaf(x2, wv.w, acc[2][3]);
            acc[3][0] = fmaf(x3, wv.x, acc[3][0]);
            acc[3][1] = fmaf(x3, wv.y, acc[3][1]);
            acc[3][2] = fmaf(x3, wv.z, acc[3][2]);
            acc[3][3] = fmaf(x3, wv.w, acc[3][3]);
        }
#pragma unroll
        for (int i = 0; i < 4; ++i) {
            int node = n0 + tr * 4 + i;
            if (node < a.N) {
                float di = a.dinv[node];
                __hip_bfloat162 p0, p1;
                p0.x = __float2bfloat16(di * acc[i][0]);
                p0.y = __float2bfloat16(di * acc[i][1]);
                p1.x = __float2bfloat16(di * acc[i][2]);
                p1.y = __float2bfloat16(di * acc[i][3]);
                __hip_bfloat162* d2 = (__hip_bfloat162*)&a.xWs[(size_t)node * 64 + tc * 4];
                d2[0] = p0;
                d2[1] = p1;
            }
        }
        __syncthreads();
    }
    grid.sync();

    // ---- P4: conv1 gather + relu + 64->2 projection ----
    {
        int o = t & 63, wv = t >> 6;
        int lim = a.NB * CAP - 1;
        float b1o = a.b1[o];
        float u0 = a.U[o * 2 + 0], u1 = a.U[o * 2 + 1];
        for (int wid = b * 4 + wv; wid < a.N; wid += gridDim.x * 4) {
            float acc = __bfloat162float(a.xWs[(size_t)wid * 64 + o]);   // self
            int beg = a.rp[wid];
            int end = beg + a.deg[wid];
            for (int base2 = beg; base2 < end; base2 += 64) {
                int nn = min(64, end - base2);
                int colv = a.colp[min(base2 + o, lim)];
                int jj = 0;
                for (; jj + 8 <= nn; jj += 8) {
                    int m0 = __shfl(colv, jj + 0);
                    int m1 = __shfl(colv, jj + 1);
                    int m2 = __shfl(colv, jj + 2);
                    int m3 = __shfl(colv, jj + 3);
                    int m4 = __shfl(colv, jj + 4);
                    int m5 = __shfl(colv, jj + 5);
                    int m6 = __shfl(colv, jj + 6);
                    int m7 = __shfl(colv, jj + 7);
                    float v0 = __bfloat162float(a.xWs[(size_t)m0 * 64 + o]);
                    float v1 = __bfloat162float(a.xWs[(size_t)m1 * 64 + o]);
                    float v2 = __bfloat162float(a.xWs[(size_t)m2 * 64 + o]);
                    float v3 = __bfloat162float(a.xWs[(size_t)m3 * 64 + o]);
                    float v4 = __bfloat162float(a.xWs[(size_t)m4 * 64 + o]);
                    float v5 = __bfloat162float(a.xWs[(size_t)m5 * 64 + o]);
                    float v6 = __bfloat162float(a.xWs[(size_t)m6 * 64 + o]);
                    float v7 = __bfloat162float(a.xWs[(size_t)m7 * 64 + o]);
                    acc += v0; acc += v1; acc += v2; acc += v3;
                    acc += v4; acc += v5; acc += v6; acc += v7;
                }
                for (; jj < nn; ++jj) {
                    int m = __shfl(colv, jj);
                    acc += __bfloat162float(a.xWs[(size_t)m * 64 + o]);
                }
            }
            float di = a.dinv[wid];
            float h = fmaxf(fmaf(di, acc, b1o), 0.f);
            float q0 = h * u0;
            float q1 = h * u1;
#pragma unroll
            for (int mm = 32; mm; mm >>= 1) {
                q0 += __shfl_xor(q0, mm);
                q1 += __shfl_xor(q1, mm);
            }
            if (o == 0) {
                a.Qs[2 * wid + 0] = di * q0;
                a.Qs[2 * wid + 1] = di * q1;
            }
        }
    }
    grid.sync();

    // ---- P5: conv2 scalar gather ----
    for (int n = b * 256 + t; n < a.N; n += GT) {
        float2 selfq = ((const float2*)a.Qs)[n];
        float p0 = selfq.x, p1 = selfq.y;
        int beg = a.rp[n], end = beg + a.deg[n];
        int j = beg;
        for (; j + 4 <= end; j += 4) {
            int m0 = a.colp[j + 0], m1 = a.colp[j + 1];
            int m2 = a.colp[j + 2], m3 = a.colp[j + 3];
            float2 q0 = ((const float2*)a.Qs)[m0];
            float2 q1 = ((const float2*)a.Qs)[m1];
            float2 q2 = ((const float2*)a.Qs)[m2];
            float2 q3 = ((const float2*)a.Qs)[m3];
            p0 += (q0.x + q1.x) + (q2.x + q3.x);
            p1 += (q0.y + q1.y) + (q2.y + q3.y);
        }
        for (; j < end; ++j) {
            float2 q = ((const float2*)a.Qs)[a.colp[j]];
            p0 += q.x;
            p1 += q.y;
        }
        float di = a.dinv[n];
        float2 pr; pr.x = di * p0; pr.y = di * p1;
        ((float2*)a.P)[n] = pr;
    }
    grid.sync();

    // ---- P6: per-edge epilogue -> fp32 out ----
    {
        float c0 = a.Cc[0], c1 = a.Cc[1], c2 = a.Cc[2], c3 = a.Cc[3];
        float c4 = a.Cc[4], c5 = a.Cc[5], c6 = a.Cc[6], c7 = a.Cc[7];
        float c8 = a.Cc[8], c9 = a.Cc[9], c10 = a.Cc[10], c11 = a.Cc[11];
        for (int e = b * 256 + t; e < a.E; e += GT) {
            int s = a.src[e], d = a.dst[e];
            float a0 = (float)a.ea[e];
            float a1 = (float)a.ea[a.E + e];
            int i2 = a.ea[2 * a.E + e], i3 = a.ea[3 * a.E + e];
            float2 ps = ((const float2*)a.P)[s];
            float2 pd = ((const float2*)a.P)[d];
            float z0 = ps.x - pd.x + a0 * c2 + a1 * c4
                     + a.E0t[i2 * 2 + 0] + a.E1t[i3 * 2 + 0] + c0;
            float z1 = ps.y - pd.y + a0 * c3 + a1 * c5
                     + a.E0t[i2 * 2 + 1] + a.E1t[i3 * 2 + 1] + c1;
            float r0 = fmaxf(z0, 0.f), r1 = fmaxf(z1, 0.f);
            float o0 = r0 * c6 + r1 * c8 + c10;
            float o1 = r0 * c7 + r1 * c9 + c11;
            float m = fmaxf(o0, o1);
            float lse = m + logf(expf(o0 - m) + expf(o1 - m));
            float2 res;
            res.x = o0 - lse;
            res.y = o1 - lse;
            ((float2*)a.out)[e] = res;
        }
    }
}

extern "C" void kernel_launch(void* const* d_in, const int* in_sizes, int n_in,
                              void* d_out, int out_size, void* d_ws, size_t ws_size,
                              hipStream_t stream) {
    MArgs a;
    a.x    = (const float*)d_in[0];
    const int* ei = (const int*)d_in[1];
    a.ea   = (const int*)d_in[2];
    a.W1   = (const float*)d_in[3];
    a.b1   = (const float*)d_in[4];
    a.W2   = (const float*)d_in[5];
    a.emb0 = (const float*)d_in[7];
    a.emb1 = (const float*)d_in[8];
    a.fcW1 = (const float*)d_in[9];
    a.fcb1 = (const float*)d_in[10];
    a.fcW2 = (const float*)d_in[11];
    a.fcb2 = (const float*)d_in[12];

    a.N = in_sizes[0] / 64;
    a.E = in_sizes[1] / 2;
    a.src = ei;
    a.dst = ei + a.E;
    a.NB = (a.N + 255) >> 8;

    // ws layout (4-byte words), ~15.6 MB (same proven budget as R8):
    char* wsb = (char*)d_ws;
    a.dinv    = (float*)wsb;                            // N
    a.rp      = (int*)(wsb + (size_t)4 * 100352);       // N
    a.deg     = (int*)(wsb + (size_t)4 * 200704);       // N
    a.cursors = (int*)(wsb + (size_t)4 * 301056);       // NB (391)
    a.U       = (float*)(wsb + (size_t)4 * 301504);     // 128
    a.E0t     = a.U + 128;                              // 40
    a.E1t     = a.E0t + 40;                             // 40
    a.Cc      = a.E1t + 40;                             // 12
    a.Qs      = (float*)(wsb + (size_t)4 * 301824);     // 2N
    a.P       = (float*)(wsb + (size_t)4 * 501824);     // 2N
    a.xWs     = (bf16*)(wsb + (size_t)4 * 701824);      // N*64 bf16 (12.8 MB)
    a.colp    = (int*)d_out;                            // NB*CAP ints (7.2 MB),
    a.out     = (float*)d_out;                          // overwritten by P6

    int blocksPerCU = 0;
    hipOccupancyMaxActiveBlocksPerMultiprocessor(&blocksPerCU, mega, 256, 0);
    if (blocksPerCU < 1) blocksPerCU = 1;
    if (blocksPerCU > 8) blocksPerCU = 8;
    int G = blocksPerCU * 256;                           // 256 CUs on MI355X

    void* params[] = { (void*)&a };
    hipLaunchCooperativeKernel((void*)mega, dim3(G), dim3(256), params, 0, stream);
}

// Round 10
// 272.343 us; speedup vs baseline: 5.0883x; 5.0883x over previous
//
#include <hip/hip_runtime.h>
#include <hip/hip_bf16.h>
#include <math.h>

// ---------------------------------------------------------------------------
// GCNWithEdge, algebraically folded + bucketed CSR gather. FP32 in/out.
//   xWs[n]   = dinv[n] * (x @ W1)[n]          (bf16, dinv folded in)
//   h1[n]    = relu(dinv[n]*(sum_{s->n} xWs[s] + xWs[n]) + b1)
//   Qs[n][c] = dinv[n] * (h1[n] . U[:,c]),  U = W2 @ fcW1[0:64,:]
//   P[n][c]  = dinv[n] * (sum_{s->n} Qs[s][c] + Qs[n][c])
//   z[e][c]  = P[s]-P[d] + a0*fcW1[64,c] + a1*fcW1[65,c] + E0t[a2]+E1t[a3]+fcb1
//   out = log_softmax( relu(z) @ fcW2 + fcb2 )
// R9 post-mortem: coop mega-kernel = 1385us (391-global-cursor atomic
// contention + grid.sync cost). Reverted to R8 multi-kernel. This round:
// gather1 8-deep (R6's 62us shape, R8's 16-deep drained at 72us), mscan3
// folded into kB/kC (offset = local-scan + part[i]), k_small merged into
// scan2 block. 11 -> 9 dispatches.
// ---------------------------------------------------------------------------

typedef __hip_bfloat16 bf16;
#define NBLK 256          // blocks for kA/kB; also the scan chunk size

// ---- kA: per-(bucket,block) histogram ----
__global__ __launch_bounds__(256) void kA(const int* __restrict__ dst,
                                          int* __restrict__ cntm,
                                          int E, int chunk, int NB) {
    __shared__ int h[512];
    int blk = blockIdx.x;
    for (int i = threadIdx.x; i < NB; i += 256) h[i] = 0;
    __syncthreads();
    int lo = blk * chunk, hi = min(E, lo + chunk);
    for (int e = lo + threadIdx.x; e < hi; e += 256)
        atomicAdd(&h[dst[e] >> 8], 1);
    __syncthreads();
    for (int i = threadIdx.x; i < NB; i += 256)
        cntm[(size_t)i * NBLK + blk] = h[i];
}

// ---- local exclusive scan of cntm chunks (chunk = 256 = one bucket row) ----
__global__ void k_mscan1(int* __restrict__ a, int* __restrict__ part, int M) {
    __shared__ int s[256];
    int i = blockIdx.x * 256 + threadIdx.x;
    int v = (i < M) ? a[i] : 0;
    s[threadIdx.x] = v;
    int x = v;
    for (int off = 1; off < 256; off <<= 1) {
        __syncthreads();
        int add = (threadIdx.x >= off) ? s[threadIdx.x - off] : 0;
        __syncthreads();
        x += add;
        s[threadIdx.x] = x;
    }
    if (i < M) a[i] = x - v;
    __syncthreads();
    if (threadIdx.x == 255) part[blockIdx.x] = s[255];
}

// ---- single block: scan part (bucket bases) + all folded tiny tables ----
__global__ __launch_bounds__(512) void k_scan2small(
        int* __restrict__ part, int B,
        const float* __restrict__ W2,
        const float* __restrict__ emb0, const float* __restrict__ emb1,
        const float* __restrict__ fcW1, const float* __restrict__ fcb1,
        const float* __restrict__ fcW2, const float* __restrict__ fcb2,
        float* __restrict__ U, float* __restrict__ E0t,
        float* __restrict__ E1t, float* __restrict__ C) {
    __shared__ int s[512];
    int t = threadIdx.x;
    int v = (t < B) ? part[t] : 0;
    s[t] = v;
    int x = v;
    for (int off = 1; off < 512; off <<= 1) {
        __syncthreads();
        int add = (t >= off) ? s[t - off] : 0;
        __syncthreads();
        x += add;
        s[t] = x;
    }
    if (t < B) part[t] = x - v;
    // tables (independent of scan)
    if (t < 128) {
        int i = t >> 1, c = t & 1;
        float sum = 0.f;
        for (int j = 0; j < 64; ++j) sum += W2[i * 64 + j] * fcW1[j * 2 + c];
        U[i * 2 + c] = sum;                       // U = W2 @ fcW1[0:64,:]
    } else if (t < 168) {
        int i = (t - 128) >> 1, c = t & 1;
        float s0 = 0.f, s1 = 0.f;
        for (int k = 0; k < 32; ++k) {
            s0 += emb0[i * 32 + k] * fcW1[(66 + k) * 2 + c];
            s1 += emb1[i * 32 + k] * fcW1[(98 + k) * 2 + c];
        }
        E0t[i * 2 + c] = s0;
        E1t[i * 2 + c] = s1;
    } else if (t == 168) {                        // b2 cancels in h2[s]-h2[d]
        C[0] = fcb1[0];  C[1] = fcb1[1];
        C[2] = fcW1[128]; C[3] = fcW1[129];
        C[4] = fcW1[130]; C[5] = fcW1[131];
        C[6] = fcW2[0];  C[7] = fcW2[1];
        C[8] = fcW2[2];  C[9] = fcW2[3];
        C[10] = fcb2[0]; C[11] = fcb2[1];
    }
}

// ---- kB: place packed pairs; global offset = local-scan + part[bucket] ----
__global__ __launch_bounds__(256) void kB(const int* __restrict__ src,
                                          const int* __restrict__ dst,
                                          const int* __restrict__ cntm,
                                          const int* __restrict__ part,
                                          int* __restrict__ pairs,
                                          int E, int chunk, int NB) {
    __shared__ int off[512];
    int blk = blockIdx.x;
    for (int i = threadIdx.x; i < NB; i += 256)
        off[i] = cntm[(size_t)i * NBLK + blk] + part[i];
    __syncthreads();
    int lo = blk * chunk, hi = min(E, lo + chunk);
    for (int e = lo + threadIdx.x; e < hi; e += 256) {
        int d = dst[e];
        int pos = atomicAdd(&off[d >> 8], 1);
        pairs[pos] = ((d & 255) << 17) | src[e];
    }
}

// ---- kC: per-bucket CSR finalize: dinv, rp, col ----
__global__ __launch_bounds__(256) void kC(const int* __restrict__ part,
                                          const int* __restrict__ pairs,
                                          int* __restrict__ col, int* __restrict__ rp,
                                          float* __restrict__ dinv,
                                          int N, int E, int NB) {
    __shared__ int cnt[256];
    __shared__ int s[256];
    int b = blockIdx.x, t = threadIdx.x;
    int n0 = b << 8;
    int nn = min(256, N - n0);
    int base = part[b];
    int end  = (b == NB - 1) ? E : part[b + 1];
    cnt[t] = 0;
    __syncthreads();
    for (int j = base + t; j < end; j += 256)
        atomicAdd(&cnt[pairs[j] >> 17], 1);
    __syncthreads();
    int v = cnt[t];
    if (t < nn) dinv[n0 + t] = rsqrtf((float)v + 1.0f);   // +1 self-loop
    s[t] = v;
    int x = v;
    for (int off = 1; off < 256; off <<= 1) {
        __syncthreads();
        int add = (t >= off) ? s[t - off] : 0;
        __syncthreads();
        x += add;
        s[t] = x;
    }
    __syncthreads();
    int excl = x - v;
    if (t < nn) rp[n0 + t] = base + excl;
    cnt[t] = base + excl;                                 // cursor
    __syncthreads();
    for (int j = base + t; j < end; j += 256) {
        int v2 = pairs[j];
        int pos = atomicAdd(&cnt[v2 >> 17], 1);
        col[pos] = v2 & 0x1FFFF;
    }
    if (b == NB - 1 && t == 0) rp[N] = E;
}

// ---------------- xWs = dinv * (x @ W1), LDS-tiled 4x4 blocking ----------------
__global__ __launch_bounds__(256) void k_gemm1(const float* __restrict__ x,
                                               const float* __restrict__ W1,
                                               const float* __restrict__ dinv,
                                               bf16* __restrict__ xWs, int N) {
    __shared__ __align__(16) float xs[64][68];
    __shared__ __align__(16) float Ws[64][64];
    int tid = threadIdx.x;
    int n0 = blockIdx.x * 64;
    for (int i = tid; i < 4096; i += 256) Ws[i >> 6][i & 63] = W1[i];
    for (int i = tid; i < 4096; i += 256) {
        int node = i >> 6, k = i & 63;
        float v = (n0 + node < N) ? x[(size_t)(n0 + node) * 64 + k] : 0.f;
        xs[k][node] = v;
    }
    __syncthreads();
    int tr = tid >> 4;
    int tc = tid & 15;
    float acc[4][4] = {};
#pragma unroll 8
    for (int k = 0; k < 64; ++k) {
        float4 xv = *(const float4*)&xs[k][tr * 4];
        float4 wv = *(const float4*)&Ws[k][tc * 4];
        acc[0][0] = fmaf(xv.x, wv.x, acc[0][0]);
        acc[0][1] = fmaf(xv.x, wv.y, acc[0][1]);
        acc[0][2] = fmaf(xv.x, wv.z, acc[0][2]);
        acc[0][3] = fmaf(xv.x, wv.w, acc[0][3]);
        acc[1][0] = fmaf(xv.y, wv.x, acc[1][0]);
        acc[1][1] = fmaf(xv.y, wv.y, acc[1][1]);
        acc[1][2] = fmaf(xv.y, wv.z, acc[1][2]);
        acc[1][3] = fmaf(xv.y, wv.w, acc[1][3]);
        acc[2][0] = fmaf(xv.z, wv.x, acc[2][0]);
        acc[2][1] = fmaf(xv.z, wv.y, acc[2][1]);
        acc[2][2] = fmaf(xv.z, wv.z, acc[2][2]);
        acc[2][3] = fmaf(xv.z, wv.w, acc[2][3]);
        acc[3][0] = fmaf(xv.w, wv.x, acc[3][0]);
        acc[3][1] = fmaf(xv.w, wv.y, acc[3][1]);
        acc[3][2] = fmaf(xv.w, wv.z, acc[3][2]);
        acc[3][3] = fmaf(xv.w, wv.w, acc[3][3]);
    }
#pragma unroll
    for (int i = 0; i < 4; ++i) {
        int node = n0 + tr * 4 + i;
        if (node < N) {
            float di = dinv[node];
            __hip_bfloat162 p0, p1;
            p0.x = __float2bfloat16(di * acc[i][0]);
            p0.y = __float2bfloat16(di * acc[i][1]);
            p1.x = __float2bfloat16(di * acc[i][2]);
            p1.y = __float2bfloat16(di * acc[i][3]);
            __hip_bfloat162* dst2 = (__hip_bfloat162*)&xWs[(size_t)node * 64 + tc * 4];
            dst2[0] = p0;
            dst2[1] = p1;
        }
    }
}

// ---- conv1 gather (8-deep, dinv folded) + relu + 64->2 projection ----
__global__ __launch_bounds__(256) void k_gather1(
        const bf16* __restrict__ xWs, const float* __restrict__ dinv,
        const int* __restrict__ rp, const int* __restrict__ col,
        const float* __restrict__ b1, const float* __restrict__ U,
        float* __restrict__ Qs, int N, int E) {
    int wid = (blockIdx.x * 256 + threadIdx.x) >> 6;
    int o = threadIdx.x & 63;
    if (wid >= N) return;
    float acc = __bfloat162float(xWs[(size_t)wid * 64 + o]);  // self (x di later)
    int beg = rp[wid], end = rp[wid + 1];
    for (int base = beg; base < end; base += 64) {
        int nn = min(64, end - base);
        int colv = col[min(base + o, E - 1)];
        int jj = 0;
        for (; jj + 8 <= nn; jj += 8) {
            int m0 = __shfl(colv, jj + 0);
            int m1 = __shfl(colv, jj + 1);
            int m2 = __shfl(colv, jj + 2);
            int m3 = __shfl(colv, jj + 3);
            int m4 = __shfl(colv, jj + 4);
            int m5 = __shfl(colv, jj + 5);
            int m6 = __shfl(colv, jj + 6);
            int m7 = __shfl(colv, jj + 7);
            float v0 = __bfloat162float(xWs[(size_t)m0 * 64 + o]);
            float v1 = __bfloat162float(xWs[(size_t)m1 * 64 + o]);
            float v2 = __bfloat162float(xWs[(size_t)m2 * 64 + o]);
            float v3 = __bfloat162float(xWs[(size_t)m3 * 64 + o]);
            float v4 = __bfloat162float(xWs[(size_t)m4 * 64 + o]);
            float v5 = __bfloat162float(xWs[(size_t)m5 * 64 + o]);
            float v6 = __bfloat162float(xWs[(size_t)m6 * 64 + o]);
            float v7 = __bfloat162float(xWs[(size_t)m7 * 64 + o]);
            acc += v0; acc += v1; acc += v2; acc += v3;
            acc += v4; acc += v5; acc += v6; acc += v7;
        }
        for (; jj < nn; ++jj) {
            int m = __shfl(colv, jj);
            acc += __bfloat162float(xWs[(size_t)m * 64 + o]);
        }
    }
    float di = dinv[wid];
    float h = fmaxf(fmaf(di, acc, b1[o]), 0.f);
    float q0 = h * U[o * 2 + 0];
    float q1 = h * U[o * 2 + 1];
#pragma unroll
    for (int mm = 32; mm; mm >>= 1) {
        q0 += __shfl_xor(q0, mm);
        q1 += __shfl_xor(q1, mm);
    }
    if (o == 0) {
        Qs[2 * wid + 0] = di * q0;
        Qs[2 * wid + 1] = di * q1;
    }
}

// ---- conv2 scalar gather (Qs pre-scaled; self-term here) ----
__global__ void k_gather2(const float* __restrict__ dinv, const int* __restrict__ rp,
                          const int* __restrict__ col, const float* __restrict__ Qs,
                          float* __restrict__ P, int N) {
    int n = blockIdx.x * blockDim.x + threadIdx.x;
    if (n >= N) return;
    float2 self = ((const float2*)Qs)[n];
    float p0 = self.x, p1 = self.y;
    int beg = rp[n], end = rp[n + 1];
    int j = beg;
    for (; j + 4 <= end; j += 4) {
        int m0 = col[j + 0], m1 = col[j + 1], m2 = col[j + 2], m3 = col[j + 3];
        float2 q0 = ((const float2*)Qs)[m0];
        float2 q1 = ((const float2*)Qs)[m1];
        float2 q2 = ((const float2*)Qs)[m2];
        float2 q3 = ((const float2*)Qs)[m3];
        p0 += (q0.x + q1.x) + (q2.x + q3.x);
        p1 += (q0.y + q1.y) + (q2.y + q3.y);
    }
    for (; j < end; ++j) {
        float2 q = ((const float2*)Qs)[col[j]];
        p0 += q.x;
        p1 += q.y;
    }
    float di = dinv[n];
    P[2 * n + 0] = di * p0;
    P[2 * n + 1] = di * p1;
}

// ---------------- per-edge epilogue -> fp32 out ----------------
__global__ void k_edge(const int* __restrict__ src, const int* __restrict__ dst,
                       const int* __restrict__ attr, const float* __restrict__ P,
                       const float* __restrict__ E0t, const float* __restrict__ E1t,
                       const float* __restrict__ C, float* __restrict__ out, int E) {
    int e = blockIdx.x * blockDim.x + threadIdx.x;
    if (e >= E) return;
    int s = src[e], d = dst[e];
    float a0 = (float)attr[e];
    float a1 = (float)attr[E + e];
    int i2 = attr[2 * E + e], i3 = attr[3 * E + e];
    const float2* P2 = (const float2*)P;
    float2 ps = P2[s], pd = P2[d];
    float z0 = ps.x - pd.x + a0 * C[2] + a1 * C[4] + E0t[i2 * 2 + 0] + E1t[i3 * 2 + 0] + C[0];
    float z1 = ps.y - pd.y + a0 * C[3] + a1 * C[5] + E0t[i2 * 2 + 1] + E1t[i3 * 2 + 1] + C[1];
    float r0 = fmaxf(z0, 0.f), r1 = fmaxf(z1, 0.f);
    float o0 = r0 * C[6] + r1 * C[8] + C[10];
    float o1 = r0 * C[7] + r1 * C[9] + C[11];
    float m = fmaxf(o0, o1);
    float lse = m + logf(expf(o0 - m) + expf(o1 - m));
    float2 res;
    res.x = o0 - lse;
    res.y = o1 - lse;
    ((float2*)out)[e] = res;
}

extern "C" void kernel_launch(void* const* d_in, const int* in_sizes, int n_in,
                              void* d_out, int out_size, void* d_ws, size_t ws_size,
                              hipStream_t stream) {
    const float* x    = (const float*)d_in[0];
    const int*   ei   = (const int*)d_in[1];
    const int*   ea   = (const int*)d_in[2];
    const float* W1   = (const float*)d_in[3];
    const float* b1   = (const float*)d_in[4];
    const float* W2   = (const float*)d_in[5];
    const float* emb0 = (const float*)d_in[7];
    const float* emb1 = (const float*)d_in[8];
    const float* fcW1 = (const float*)d_in[9];
    const float* fcb1 = (const float*)d_in[10];
    const float* fcW2 = (const float*)d_in[11];
    const float* fcb2 = (const float*)d_in[12];

    const int N = in_sizes[0] / 64;
    const int E = in_sizes[1] / 2;
    const int* src = ei;
    const int* dst = ei + E;
    const int NB = (N + 255) >> 8;                // buckets of 256 nodes (391)
    const int NBB = NB * NBLK;                    // count-matrix size (~100K)
    const int chunk = (E + NBLK - 1) / NBLK;
    const int BS = (NBB + 255) / 256;             // scan chunks == NB (<=512)

    // ws layout (4-byte words), ~15.6 MB:
    char* wsb = (char*)d_ws;
    float* dinv = (float*)wsb;                             // N
    int*   rp   = (int*)(wsb + (size_t)4 * 100352);        // N+1
    int*   cntm = (int*)(wsb + (size_t)4 * 200704);        // NBB
    int*   part = (int*)(wsb + (size_t)4 * 300800);        // 512
    float* U    = (float*)(wsb + (size_t)4 * 301312);      // 128
    float* E0t  = U + 128;                                 // 40
    float* E1t  = E0t + 40;                                // 40
    float* C    = E1t + 40;                                // 12
    float* Qs   = (float*)(wsb + (size_t)4 * 301568);      // 2N
    float* P    = (float*)(wsb + (size_t)4 * 501760);      // 2N
    bf16*  xWs  = (bf16*)(wsb + (size_t)4 * 702464);       // N*64 bf16 (12.8 MB)
    int*   col   = (int*)d_out;                            // E ints (first half)
    int*   pairs = (int*)d_out + E;                        // E ints (second half)
    // col+pairs = 2E ints = exactly out_size floats; k_edge overwrites last.

    kA<<<NBLK, 256, 0, stream>>>(dst, cntm, E, chunk, NB);
    k_mscan1<<<BS, 256, 0, stream>>>(cntm, part, NBB);
    k_scan2small<<<1, 512, 0, stream>>>(part, BS, W2, emb0, emb1, fcW1, fcb1,
                                        fcW2, fcb2, U, E0t, E1t, C);
    kB<<<NBLK, 256, 0, stream>>>(src, dst, cntm, part, pairs, E, chunk, NB);
    kC<<<NB, 256, 0, stream>>>(part, pairs, col, rp, dinv, N, E, NB);
    k_gemm1<<<(N + 63) / 64, 256, 0, stream>>>(x, W1, dinv, xWs, N);
    k_gather1<<<((size_t)N * 64 + 255) / 256, 256, 0, stream>>>(xWs, dinv, rp, col, b1, U, Qs, N, E);
    k_gather2<<<(N + 255) / 256, 256, 0, stream>>>(dinv, rp, col, Qs, P, N);
    k_edge<<<(E + 255) / 256, 256, 0, stream>>>(src, dst, ea, P, E0t, E1t, C,
                                                (float*)d_out, E);
}

// Round 11
// 253.171 us; speedup vs baseline: 5.4736x; 1.0757x over previous
//
#include <hip/hip_runtime.h>
#include <hip/hip_bf16.h>
#include <math.h>

// ---------------------------------------------------------------------------
// GCNWithEdge, algebraically folded + bucketed CSR gather. FP32 in/out.
//   xWs[n]   = dinv[n] * (x @ W1)[n]          (bf16, dinv folded in)
//   h1[n]    = relu(dinv[n]*(sum_{s->n} xWs[s] + xWs[n]) + b1)
//   Qs[n][c] = dinv[n] * (h1[n] . U[:,c]),  U = W2 @ fcW1[0:64,:]
//   P[n][c]  = dinv[n] * (sum_{s->n} Qs[s][c] + Qs[n][c])
//   z[e][c]  = P[s]-P[d] + a0*fcW1[64,c] + a1*fcW1[65,c] + E0t[a2]+E1t[a3]+fcb1
//   out = log_softmax( relu(z) @ fcW2 + fcb2 )
// R11: gather1 restructured to 32-lane/node bf16x2 loads (2 nodes per wave,
// half-wave segments) -> half the load/addr/shfl instructions per edge, 2x
// load slots in flight. gemm1 x-tile pad 68->66 (8-way LDS write conflict ->
// free 2-way), float2 reads (alignment). Rest identical to R10 (272us).
// ---------------------------------------------------------------------------

typedef __hip_bfloat16 bf16;
#define NBLK 256          // blocks for kA/kB; also the scan chunk size

// ---- kA: per-(bucket,block) histogram ----
__global__ __launch_bounds__(256) void kA(const int* __restrict__ dst,
                                          int* __restrict__ cntm,
                                          int E, int chunk, int NB) {
    __shared__ int h[512];
    int blk = blockIdx.x;
    for (int i = threadIdx.x; i < NB; i += 256) h[i] = 0;
    __syncthreads();
    int lo = blk * chunk, hi = min(E, lo + chunk);
    for (int e = lo + threadIdx.x; e < hi; e += 256)
        atomicAdd(&h[dst[e] >> 8], 1);
    __syncthreads();
    for (int i = threadIdx.x; i < NB; i += 256)
        cntm[(size_t)i * NBLK + blk] = h[i];
}

// ---- local exclusive scan of cntm chunks (chunk = 256 = one bucket row) ----
__global__ void k_mscan1(int* __restrict__ a, int* __restrict__ part, int M) {
    __shared__ int s[256];
    int i = blockIdx.x * 256 + threadIdx.x;
    int v = (i < M) ? a[i] : 0;
    s[threadIdx.x] = v;
    int x = v;
    for (int off = 1; off < 256; off <<= 1) {
        __syncthreads();
        int add = (threadIdx.x >= off) ? s[threadIdx.x - off] : 0;
        __syncthreads();
        x += add;
        s[threadIdx.x] = x;
    }
    if (i < M) a[i] = x - v;
    __syncthreads();
    if (threadIdx.x == 255) part[blockIdx.x] = s[255];
}

// ---- single block: scan part (bucket bases) + all folded tiny tables ----
__global__ __launch_bounds__(512) void k_scan2small(
        int* __restrict__ part, int B,
        const float* __restrict__ W2,
        const float* __restrict__ emb0, const float* __restrict__ emb1,
        const float* __restrict__ fcW1, const float* __restrict__ fcb1,
        const float* __restrict__ fcW2, const float* __restrict__ fcb2,
        float* __restrict__ U, float* __restrict__ E0t,
        float* __restrict__ E1t, float* __restrict__ C) {
    __shared__ int s[512];
    int t = threadIdx.x;
    int v = (t < B) ? part[t] : 0;
    s[t] = v;
    int x = v;
    for (int off = 1; off < 512; off <<= 1) {
        __syncthreads();
        int add = (t >= off) ? s[t - off] : 0;
        __syncthreads();
        x += add;
        s[t] = x;
    }
    if (t < B) part[t] = x - v;
    // tables (independent of scan)
    if (t < 128) {
        int i = t >> 1, c = t & 1;
        float sum = 0.f;
        for (int j = 0; j < 64; ++j) sum += W2[i * 64 + j] * fcW1[j * 2 + c];
        U[i * 2 + c] = sum;                       // U = W2 @ fcW1[0:64,:]
    } else if (t < 168) {
        int i = (t - 128) >> 1, c = t & 1;
        float s0 = 0.f, s1 = 0.f;
        for (int k = 0; k < 32; ++k) {
            s0 += emb0[i * 32 + k] * fcW1[(66 + k) * 2 + c];
            s1 += emb1[i * 32 + k] * fcW1[(98 + k) * 2 + c];
        }
        E0t[i * 2 + c] = s0;
        E1t[i * 2 + c] = s1;
    } else if (t == 168) {                        // b2 cancels in h2[s]-h2[d]
        C[0] = fcb1[0];  C[1] = fcb1[1];
        C[2] = fcW1[128]; C[3] = fcW1[129];
        C[4] = fcW1[130]; C[5] = fcW1[131];
        C[6] = fcW2[0];  C[7] = fcW2[1];
        C[8] = fcW2[2];  C[9] = fcW2[3];
        C[10] = fcb2[0]; C[11] = fcb2[1];
    }
}

// ---- kB: place packed pairs; global offset = local-scan + part[bucket] ----
__global__ __launch_bounds__(256) void kB(const int* __restrict__ src,
                                          const int* __restrict__ dst,
                                          const int* __restrict__ cntm,
                                          const int* __restrict__ part,
                                          int* __restrict__ pairs,
                                          int E, int chunk, int NB) {
    __shared__ int off[512];
    int blk = blockIdx.x;
    for (int i = threadIdx.x; i < NB; i += 256)
        off[i] = cntm[(size_t)i * NBLK + blk] + part[i];
    __syncthreads();
    int lo = blk * chunk, hi = min(E, lo + chunk);
    for (int e = lo + threadIdx.x; e < hi; e += 256) {
        int d = dst[e];
        int pos = atomicAdd(&off[d >> 8], 1);
        pairs[pos] = ((d & 255) << 17) | src[e];
    }
}

// ---- kC: per-bucket CSR finalize: dinv, rp, col ----
__global__ __launch_bounds__(256) void kC(const int* __restrict__ part,
                                          const int* __restrict__ pairs,
                                          int* __restrict__ col, int* __restrict__ rp,
                                          float* __restrict__ dinv,
                                          int N, int E, int NB) {
    __shared__ int cnt[256];
    __shared__ int s[256];
    int b = blockIdx.x, t = threadIdx.x;
    int n0 = b << 8;
    int nn = min(256, N - n0);
    int base = part[b];
    int end  = (b == NB - 1) ? E : part[b + 1];
    cnt[t] = 0;
    __syncthreads();
    for (int j = base + t; j < end; j += 256)
        atomicAdd(&cnt[pairs[j] >> 17], 1);
    __syncthreads();
    int v = cnt[t];
    if (t < nn) dinv[n0 + t] = rsqrtf((float)v + 1.0f);   // +1 self-loop
    s[t] = v;
    int x = v;
    for (int off = 1; off < 256; off <<= 1) {
        __syncthreads();
        int add = (t >= off) ? s[t - off] : 0;
        __syncthreads();
        x += add;
        s[t] = x;
    }
    __syncthreads();
    int excl = x - v;
    if (t < nn) rp[n0 + t] = base + excl;
    cnt[t] = base + excl;                                 // cursor
    __syncthreads();
    for (int j = base + t; j < end; j += 256) {
        int v2 = pairs[j];
        int pos = atomicAdd(&cnt[v2 >> 17], 1);
        col[pos] = v2 & 0x1FFFF;
    }
    if (b == NB - 1 && t == 0) rp[N] = E;
}

// ---------------- xWs = dinv * (x @ W1), LDS-tiled 4x4 blocking ----------------
__global__ __launch_bounds__(256) void k_gemm1(const float* __restrict__ x,
                                               const float* __restrict__ W1,
                                               const float* __restrict__ dinv,
                                               bf16* __restrict__ xWs, int N) {
    __shared__ __align__(16) float xs[64][66];   // pad 66: write stride 2 banks (free)
    __shared__ __align__(16) float Ws[64][64];
    int tid = threadIdx.x;
    int n0 = blockIdx.x * 64;
    for (int i = tid; i < 4096; i += 256) Ws[i >> 6][i & 63] = W1[i];
    for (int i = tid; i < 4096; i += 256) {
        int node = i >> 6, k = i & 63;
        float v = (n0 + node < N) ? x[(size_t)(n0 + node) * 64 + k] : 0.f;
        xs[k][node] = v;
    }
    __syncthreads();
    int tr = tid >> 4;
    int tc = tid & 15;
    float acc[4][4] = {};
#pragma unroll 8
    for (int k = 0; k < 64; ++k) {
        float2 xa = *(const float2*)&xs[k][tr * 4];
        float2 xb = *(const float2*)&xs[k][tr * 4 + 2];
        float4 wv = *(const float4*)&Ws[k][tc * 4];
        acc[0][0] = fmaf(xa.x, wv.x, acc[0][0]);
        acc[0][1] = fmaf(xa.x, wv.y, acc[0][1]);
        acc[0][2] = fmaf(xa.x, wv.z, acc[0][2]);
        acc[0][3] = fmaf(xa.x, wv.w, acc[0][3]);
        acc[1][0] = fmaf(xa.y, wv.x, acc[1][0]);
        acc[1][1] = fmaf(xa.y, wv.y, acc[1][1]);
        acc[1][2] = fmaf(xa.y, wv.z, acc[1][2]);
        acc[1][3] = fmaf(xa.y, wv.w, acc[1][3]);
        acc[2][0] = fmaf(xb.x, wv.x, acc[2][0]);
        acc[2][1] = fmaf(xb.x, wv.y, acc[2][1]);
        acc[2][2] = fmaf(xb.x, wv.z, acc[2][2]);
        acc[2][3] = fmaf(xb.x, wv.w, acc[2][3]);
        acc[3][0] = fmaf(xb.y, wv.x, acc[3][0]);
        acc[3][1] = fmaf(xb.y, wv.y, acc[3][1]);
        acc[3][2] = fmaf(xb.y, wv.z, acc[3][2]);
        acc[3][3] = fmaf(xb.y, wv.w, acc[3][3]);
    }
#pragma unroll
    for (int i = 0; i < 4; ++i) {
        int node = n0 + tr * 4 + i;
        if (node < N) {
            float di = dinv[node];
            __hip_bfloat162 p0, p1;
            p0.x = __float2bfloat16(di * acc[i][0]);
            p0.y = __float2bfloat16(di * acc[i][1]);
            p1.x = __float2bfloat16(di * acc[i][2]);
            p1.y = __float2bfloat16(di * acc[i][3]);
            __hip_bfloat162* dst2 = (__hip_bfloat162*)&xWs[(size_t)node * 64 + tc * 4];
            dst2[0] = p0;
            dst2[1] = p1;
        }
    }
}

// ---- conv1 gather: 32 lanes/node, bf16x2/lane, 2 nodes per wave ----
__global__ __launch_bounds__(256) void k_gather1(
        const bf16* __restrict__ xWs, const float* __restrict__ dinv,
        const int* __restrict__ rp, const int* __restrict__ col,
        const float* __restrict__ b1, const float* __restrict__ U,
        float* __restrict__ Qs, int N, int E) {
    int wid = blockIdx.x * 8 + (threadIdx.x >> 5);   // node id (8 per block)
    int c = threadIdx.x & 31;                        // channel pair: 2c, 2c+1
    if (wid >= N) return;
    const __hip_bfloat162* xW2 = (const __hip_bfloat162*)xWs;  // [n*32 + c]
    __hip_bfloat162 sv = xW2[(size_t)wid * 32 + c];
    float ax = __bfloat162float(sv.x);
    float ay = __bfloat162float(sv.y);
    int beg = rp[wid], end = rp[wid + 1];
    for (int base = beg; base < end; base += 32) {
        int nn = min(32, end - base);
        int colv = col[min(base + c, E - 1)];
        int jj = 0;
        for (; jj + 8 <= nn; jj += 8) {
            int m0 = __shfl(colv, jj + 0, 32);
            int m1 = __shfl(colv, jj + 1, 32);
            int m2 = __shfl(colv, jj + 2, 32);
            int m3 = __shfl(colv, jj + 3, 32);
            int m4 = __shfl(colv, jj + 4, 32);
            int m5 = __shfl(colv, jj + 5, 32);
            int m6 = __shfl(colv, jj + 6, 32);
            int m7 = __shfl(colv, jj + 7, 32);
            __hip_bfloat162 v0 = xW2[(size_t)m0 * 32 + c];
            __hip_bfloat162 v1 = xW2[(size_t)m1 * 32 + c];
            __hip_bfloat162 v2 = xW2[(size_t)m2 * 32 + c];
            __hip_bfloat162 v3 = xW2[(size_t)m3 * 32 + c];
            __hip_bfloat162 v4 = xW2[(size_t)m4 * 32 + c];
            __hip_bfloat162 v5 = xW2[(size_t)m5 * 32 + c];
            __hip_bfloat162 v6 = xW2[(size_t)m6 * 32 + c];
            __hip_bfloat162 v7 = xW2[(size_t)m7 * 32 + c];
            ax += __bfloat162float(v0.x); ay += __bfloat162float(v0.y);
            ax += __bfloat162float(v1.x); ay += __bfloat162float(v1.y);
            ax += __bfloat162float(v2.x); ay += __bfloat162float(v2.y);
            ax += __bfloat162float(v3.x); ay += __bfloat162float(v3.y);
            ax += __bfloat162float(v4.x); ay += __bfloat162float(v4.y);
            ax += __bfloat162float(v5.x); ay += __bfloat162float(v5.y);
            ax += __bfloat162float(v6.x); ay += __bfloat162float(v6.y);
            ax += __bfloat162float(v7.x); ay += __bfloat162float(v7.y);
        }
        for (; jj < nn; ++jj) {
            int m = __shfl(colv, jj, 32);
            __hip_bfloat162 v = xW2[(size_t)m * 32 + c];
            ax += __bfloat162float(v.x);
            ay += __bfloat162float(v.y);
        }
    }
    float di = dinv[wid];
    float2 b1v = ((const float2*)b1)[c];
    float h0 = fmaxf(fmaf(di, ax, b1v.x), 0.f);
    float h1 = fmaxf(fmaf(di, ay, b1v.y), 0.f);
    float4 Uv = ((const float4*)U)[c];   // {U[2c][0],U[2c][1],U[2c+1][0],U[2c+1][1]}
    float q0 = fmaf(h0, Uv.x, h1 * Uv.z);
    float q1 = fmaf(h0, Uv.y, h1 * Uv.w);
#pragma unroll
    for (int mm = 16; mm; mm >>= 1) {
        q0 += __shfl_xor(q0, mm);        // xor<32 stays within half-wave
        q1 += __shfl_xor(q1, mm);
    }
    if (c == 0) {
        Qs[2 * wid + 0] = di * q0;
        Qs[2 * wid + 1] = di * q1;
    }
}

// ---- conv2 scalar gather (Qs pre-scaled; self-term here) ----
__global__ void k_gather2(const float* __restrict__ dinv, const int* __restrict__ rp,
                          const int* __restrict__ col, const float* __restrict__ Qs,
                          float* __restrict__ P, int N) {
    int n = blockIdx.x * blockDim.x + threadIdx.x;
    if (n >= N) return;
    float2 self = ((const float2*)Qs)[n];
    float p0 = self.x, p1 = self.y;
    int beg = rp[n], end = rp[n + 1];
    int j = beg;
    for (; j + 4 <= end; j += 4) {
        int m0 = col[j + 0], m1 = col[j + 1], m2 = col[j + 2], m3 = col[j + 3];
        float2 q0 = ((const float2*)Qs)[m0];
        float2 q1 = ((const float2*)Qs)[m1];
        float2 q2 = ((const float2*)Qs)[m2];
        float2 q3 = ((const float2*)Qs)[m3];
        p0 += (q0.x + q1.x) + (q2.x + q3.x);
        p1 += (q0.y + q1.y) + (q2.y + q3.y);
    }
    for (; j < end; ++j) {
        float2 q = ((const float2*)Qs)[col[j]];
        p0 += q.x;
        p1 += q.y;
    }
    float di = dinv[n];
    P[2 * n + 0] = di * p0;
    P[2 * n + 1] = di * p1;
}

// ---------------- per-edge epilogue -> fp32 out ----------------
__global__ void k_edge(const int* __restrict__ src, const int* __restrict__ dst,
                       const int* __restrict__ attr, const float* __restrict__ P,
                       const float* __restrict__ E0t, const float* __restrict__ E1t,
                       const float* __restrict__ C, float* __restrict__ out, int E) {
    int e = blockIdx.x * blockDim.x + threadIdx.x;
    if (e >= E) return;
    int s = src[e], d = dst[e];
    float a0 = (float)attr[e];
    float a1 = (float)attr[E + e];
    int i2 = attr[2 * E + e], i3 = attr[3 * E + e];
    const float2* P2 = (const float2*)P;
    float2 ps = P2[s], pd = P2[d];
    float z0 = ps.x - pd.x + a0 * C[2] + a1 * C[4] + E0t[i2 * 2 + 0] + E1t[i3 * 2 + 0] + C[0];
    float z1 = ps.y - pd.y + a0 * C[3] + a1 * C[5] + E0t[i2 * 2 + 1] + E1t[i3 * 2 + 1] + C[1];
    float r0 = fmaxf(z0, 0.f), r1 = fmaxf(z1, 0.f);
    float o0 = r0 * C[6] + r1 * C[8] + C[10];
    float o1 = r0 * C[7] + r1 * C[9] + C[11];
    float m = fmaxf(o0, o1);
    float lse = m + logf(expf(o0 - m) + expf(o1 - m));
    float2 res;
    res.x = o0 - lse;
    res.y = o1 - lse;
    ((float2*)out)[e] = res;
}

extern "C" void kernel_launch(void* const* d_in, const int* in_sizes, int n_in,
                              void* d_out, int out_size, void* d_ws, size_t ws_size,
                              hipStream_t stream) {
    const float* x    = (const float*)d_in[0];
    const int*   ei   = (const int*)d_in[1];
    const int*   ea   = (const int*)d_in[2];
    const float* W1   = (const float*)d_in[3];
    const float* b1   = (const float*)d_in[4];
    const float* W2   = (const float*)d_in[5];
    const float* emb0 = (const float*)d_in[7];
    const float* emb1 = (const float*)d_in[8];
    const float* fcW1 = (const float*)d_in[9];
    const float* fcb1 = (const float*)d_in[10];
    const float* fcW2 = (const float*)d_in[11];
    const float* fcb2 = (const float*)d_in[12];

    const int N = in_sizes[0] / 64;
    const int E = in_sizes[1] / 2;
    const int* src = ei;
    const int* dst = ei + E;
    const int NB = (N + 255) >> 8;                // buckets of 256 nodes (391)
    const int NBB = NB * NBLK;                    // count-matrix size (~100K)
    const int chunk = (E + NBLK - 1) / NBLK;
    const int BS = (NBB + 255) / 256;             // scan chunks == NB (<=512)

    // ws layout (4-byte words), ~15.6 MB:
    char* wsb = (char*)d_ws;
    float* dinv = (float*)wsb;                             // N
    int*   rp   = (int*)(wsb + (size_t)4 * 100352);        // N+1
    int*   cntm = (int*)(wsb + (size_t)4 * 200704);        // NBB
    int*   part = (int*)(wsb + (size_t)4 * 300800);        // 512
    float* U    = (float*)(wsb + (size_t)4 * 301312);      // 128
    float* E0t  = U + 128;                                 // 40
    float* E1t  = E0t + 40;                                // 40
    float* C    = E1t + 40;                                // 12
    float* Qs   = (float*)(wsb + (size_t)4 * 301568);      // 2N
    float* P    = (float*)(wsb + (size_t)4 * 501760);      // 2N
    bf16*  xWs  = (bf16*)(wsb + (size_t)4 * 702464);       // N*64 bf16 (12.8 MB)
    int*   col   = (int*)d_out;                            // E ints (first half)
    int*   pairs = (int*)d_out + E;                        // E ints (second half)
    // col+pairs = 2E ints = exactly out_size floats; k_edge overwrites last.

    kA<<<NBLK, 256, 0, stream>>>(dst, cntm, E, chunk, NB);
    k_mscan1<<<BS, 256, 0, stream>>>(cntm, part, NBB);
    k_scan2small<<<1, 512, 0, stream>>>(part, BS, W2, emb0, emb1, fcW1, fcb1,
                                        fcW2, fcb2, U, E0t, E1t, C);
    kB<<<NBLK, 256, 0, stream>>>(src, dst, cntm, part, pairs, E, chunk, NB);
    kC<<<NB, 256, 0, stream>>>(part, pairs, col, rp, dinv, N, E, NB);
    k_gemm1<<<(N + 63) / 64, 256, 0, stream>>>(x, W1, dinv, xWs, N);
    k_gather1<<<(N + 7) / 8, 256, 0, stream>>>(xWs, dinv, rp, col, b1, U, Qs, N, E);
    k_gather2<<<(N + 255) / 256, 256, 0, stream>>>(dinv, rp, col, Qs, P, N);
    k_edge<<<(E + 255) / 256, 256, 0, stream>>>(src, dst, ea, P, E0t, E1t, C,
                                                (float*)d_out, E);
}